// Round 3
// baseline (2637.616 us; speedup 1.0000x reference)
//
#include <hip/hip_runtime.h>
#include <hip/hip_bf16.h>
#include <math.h>

#define PN   2048
#define PB   16
#define PG   128
#define PM   32
#define PDM  384
#define PDI  768
#define ROWS 2048   // B*G == B*L

typedef unsigned short ushort_t;
typedef __attribute__((ext_vector_type(8))) short bf8;
typedef __attribute__((ext_vector_type(4))) float f4;

__device__ __forceinline__ ushort_t f2bf(float x) {
  unsigned int u = __float_as_uint(x);
  unsigned int r = (u + 0x7FFFu + ((u >> 16) & 1u)) >> 16;
  return (ushort_t)r;
}

#define GL2L(gp, lp) __builtin_amdgcn_global_load_lds((const __attribute__((address_space(1))) void*)(gp), (__attribute__((address_space(3))) void*)(lp), 16, 0, 0)

// ---------------------------------------------------------------- all weight fp32->bf16 in one launch
// regions: e1w2(32768) e2w1(262144) e2w2(196608) in_w(7077888) out_w(3538944)
#define CV_O1 32768
#define CV_O2 294912
#define CV_O3 491520
#define CV_O4 7569408
#define CV_TOT 11108352
__global__ __launch_bounds__(256) void cvt_all_kernel(
    const float* __restrict__ e1w2, const float* __restrict__ e2w1,
    const float* __restrict__ e2w2, const float* __restrict__ in_w,
    const float* __restrict__ out_w, ushort_t* __restrict__ wb) {
  int i = blockIdx.x*256 + threadIdx.x;
  if (i >= CV_TOT) return;
  const float* s; int off;
  if      (i < CV_O1) { s = e1w2;  off = 0; }
  else if (i < CV_O2) { s = e2w1;  off = CV_O1; }
  else if (i < CV_O3) { s = e2w2;  off = CV_O2; }
  else if (i < CV_O4) { s = in_w;  off = CV_O3; }
  else                { s = out_w; off = CV_O4; }
  wb[i] = f2bf(s[i - off]);
}

// ---------------------------------------------------------------- dt_w transpose (12,768,24)->(12,24,768)
__global__ __launch_bounds__(256) void dtw_t_kernel(const float* __restrict__ dtw,
                                                    float* __restrict__ dtwT) {
  int i = blockIdx.x*256 + threadIdx.x;
  if (i >= 12*768*24) return;
  int layer = i / (768*24);
  int rem = i - layer*768*24;
  int d = rem / 24, r = rem - d*24;
  dtwT[layer*24*768 + r*768 + d] = dtw[i];
}

// ---------------------------------------------------------------- FPS: one wave per batch, state in regs
__global__ __launch_bounds__(64) void fps_kernel(const float* __restrict__ xyz,
                                                 int* __restrict__ cidx) {
  const int b = blockIdx.x;
  const int lane = threadIdx.x;
  __shared__ float pts[PN*3];
  const float* base = xyz + (size_t)b * PN * 3;
  for (int t = lane; t < PN*3; t += 64) pts[t] = base[t];
  __syncthreads();
  float px[32], py[32], pz[32], dmin[32];
  #pragma unroll
  for (int j = 0; j < 32; ++j) {
    int idx = j*64 + lane;
    px[j] = pts[idx*3+0]; py[j] = pts[idx*3+1]; pz[j] = pts[idx*3+2];
    dmin[j] = 1e10f;
  }
  int cur = 0;
  for (int g = 0; g < PG; ++g) {
    if (lane == 0) cidx[b*PG + g] = cur;
    const float cx = pts[cur*3+0], cy = pts[cur*3+1], cz = pts[cur*3+2];
    float bestv = -1.0f; int besti = 0;
    #pragma unroll
    for (int j = 0; j < 32; ++j) {
      float dx = __fsub_rn(px[j], cx);
      float dy = __fsub_rn(py[j], cy);
      float dz = __fsub_rn(pz[j], cz);
      float dd = __fadd_rn(__fadd_rn(__fmul_rn(dx,dx), __fmul_rn(dy,dy)), __fmul_rn(dz,dz));
      float dm = fminf(dmin[j], dd);
      dmin[j] = dm;
      if (dm > bestv) { bestv = dm; besti = j*64 + lane; }
    }
    #pragma unroll
    for (int off = 1; off < 64; off <<= 1) {
      float ov = __shfl_xor(bestv, off);
      int   oi = __shfl_xor(besti, off);
      if (ov > bestv || (ov == bestv && oi < besti)) { bestv = ov; besti = oi; }
    }
    cur = __builtin_amdgcn_readfirstlane(besti);
  }
}

// ---------------------------------------------------------------- kNN: one wave per group, d2 in regs
__global__ __launch_bounds__(64) void knn_kernel(const float* __restrict__ xyz,
                                                 const int* __restrict__ cidx,
                                                 float* __restrict__ nbx,
                                                 float* __restrict__ centerb) {
  const int bg = blockIdx.x;
  const int b = bg >> 7;
  const int lane = threadIdx.x;
  const float* base = xyz + (size_t)b * PN * 3;
  const int ci = cidx[bg];
  const float cx = base[ci*3+0], cy = base[ci*3+1], cz = base[ci*3+2];
  if (lane == 0) { centerb[bg*3+0]=cx; centerb[bg*3+1]=cy; centerb[bg*3+2]=cz; }
  float d2[32];
  #pragma unroll
  for (int j = 0; j < 32; ++j) {
    int idx = j*64 + lane;
    float dx = __fsub_rn(cx, base[idx*3+0]);
    float dy = __fsub_rn(cy, base[idx*3+1]);
    float dz = __fsub_rn(cz, base[idx*3+2]);
    d2[j] = __fadd_rn(__fadd_rn(__fmul_rn(dx,dx), __fmul_rn(dy,dy)), __fmul_rn(dz,dz));
  }
  for (int m = 0; m < PM; ++m) {
    float bestv = 1e38f; int besti = 0x7fffffff;
    #pragma unroll
    for (int j = 0; j < 32; ++j) {
      int idx = j*64 + lane;
      if (d2[j] < bestv) { bestv = d2[j]; besti = idx; }   // ascending idx -> first on tie
    }
    #pragma unroll
    for (int off = 1; off < 64; off <<= 1) {
      float ov = __shfl_xor(bestv, off);
      int   oi = __shfl_xor(besti, off);
      if (ov < bestv || (ov == bestv && oi < besti)) { bestv = ov; besti = oi; }
    }
    const int k = __builtin_amdgcn_readfirstlane(besti);
    const int jwin = k >> 6, owner = k & 63;
    #pragma unroll
    for (int j = 0; j < 32; ++j)
      if (j == jwin && lane == owner) d2[j] = 1e38f;
    if (lane == 0) {
      nbx[(bg*PM + m)*3 + 0] = base[k*3+0] - cx;
      nbx[(bg*PM + m)*3 + 1] = base[k*3+1] - cy;
      nbx[(bg*PM + m)*3 + 2] = base[k*3+2] - cz;
    }
  }
}

// ---------------------------------------------------------------- embed stage A (fp32 VALU) + stage B (MFMA) -> concat bf16
// concat[row=bg*32+m][c]: c<256 -> group max of f2, c>=256 -> f2[m][c-256]
__global__ __launch_bounds__(256) void embed1_kernel(
    const float* __restrict__ nbx,
    const float* __restrict__ e1w1, const float* __restrict__ e1b1,
    const float* __restrict__ bn1g, const float* __restrict__ bn1b,
    const ushort_t* __restrict__ e1w2b, const float* __restrict__ e1b2,
    ushort_t* __restrict__ concat) {
  const int bg = blockIdx.x;
  const int tid = threadIdx.x;
  const int wid = tid >> 6, lane = tid & 63;
  const int q = lane >> 4, r16 = lane & 15;
  __shared__ float xs[PM*3];
  __shared__ __align__(16) ushort_t Af[4*2*64*8];   // [kc][t][lane][8], 8 KB
  __shared__ __align__(16) ushort_t Bs[16*64*8];    // per-kc B tiles, 16 KB
  if (tid < PM*3) xs[tid] = nbx[bg*PM*3 + tid];
  __syncthreads();
  const float bnscale = rsqrtf(1.0f + 1e-5f);
  #pragma unroll
  for (int it = 0; it < 16; ++it) {
    int id = tid + it*256;
    int m = id >> 7, c = id & 127;
    float v = xs[m*3+0]*e1w1[c*3+0] + xs[m*3+1]*e1w1[c*3+1] + xs[m*3+2]*e1w1[c*3+2] + e1b1[c];
    v = v * (bn1g[c]*bnscale) + bn1b[c];
    v = fmaxf(v, 0.0f);
    int kc = c >> 5, cc = c & 31, qq = cc >> 3, j = cc & 7;
    int t = m >> 4, r = m & 15;
    Af[((kc*2 + t)*64 + qq*16 + r)*8 + j] = f2bf(v);
  }
  f4 acc[2][4];
  #pragma unroll
  for (int t = 0; t < 2; ++t)
    #pragma unroll
    for (int jj = 0; jj < 4; ++jj) { f4 z = {0.f,0.f,0.f,0.f}; acc[t][jj] = z; }
  for (int kc = 0; kc < 4; ++kc) {
    #pragma unroll
    for (int u = wid; u < 16; u += 4)
      GL2L(e1w2b + (size_t)(u*16 + r16)*128 + kc*32 + q*8, Bs + u*512);
    __syncthreads();
    bf8 a0 = *(const bf8*)(Af + ((size_t)((kc*2+0)*64 + lane))*8);
    bf8 a1 = *(const bf8*)(Af + ((size_t)((kc*2+1)*64 + lane))*8);
    #pragma unroll
    for (int jj = 0; jj < 4; ++jj) {
      bf8 bv = *(const bf8*)(Bs + ((size_t)((wid*4+jj)*64 + lane))*8);
      acc[0][jj] = __builtin_amdgcn_mfma_f32_16x16x32_bf16(a0, bv, acc[0][jj], 0, 0, 0);
      acc[1][jj] = __builtin_amdgcn_mfma_f32_16x16x32_bf16(a1, bv, acc[1][jj], 0, 0, 0);
    }
    __syncthreads();
  }
  // epilogue: +bias, column max over 32 rows, write concat
  #pragma unroll
  for (int jj = 0; jj < 4; ++jj) {
    const int n = (wid*4+jj)*16 + r16;
    const float bias = e1b2[n];
    float v0[4], v1[4];
    float cm = -1e30f;
    #pragma unroll
    for (int rr = 0; rr < 4; ++rr) {
      v0[rr] = acc[0][jj][rr] + bias;
      v1[rr] = acc[1][jj][rr] + bias;
      cm = fmaxf(cm, fmaxf(v0[rr], v1[rr]));
    }
    cm = fmaxf(cm, __shfl_xor(cm, 16));
    cm = fmaxf(cm, __shfl_xor(cm, 32));
    ushort_t mxb = f2bf(cm);
    #pragma unroll
    for (int rr = 0; rr < 4; ++rr) {
      size_t base0 = ((size_t)bg*32 + q*4 + rr)*512;
      size_t base1 = ((size_t)bg*32 + 16 + q*4 + rr)*512;
      concat[base0 + 256 + n] = f2bf(v0[rr]);
      concat[base1 + 256 + n] = f2bf(v1[rr]);
      concat[base0 + n] = mxb;
      concat[base1 + n] = mxb;
    }
  }
}

// ---------------------------------------------------------------- bf16 MFMA GEMM  C = A(M,K) @ W(N,K)^T
template<int MT, int NT, int EPI>
__global__ __launch_bounds__(256) void mfma_gemm(
    const ushort_t* __restrict__ A, int lda,
    const ushort_t* __restrict__ W, int ldw,
    float* __restrict__ Cf, ushort_t* __restrict__ Cb, int ldc, int K,
    const float* __restrict__ p0, const float* __restrict__ p1,
    const float* __restrict__ p2) {
  static_assert(EPI != 2 || MT == 4, "groupmax needs MT=4");
  constexpr int AT = 2*MT, BT = 2*NT;
  __shared__ __align__(16) ushort_t As[AT*64*8];
  __shared__ __align__(16) ushort_t Bs[BT*64*8];
  const int tid = threadIdx.x;
  const int wid = tid >> 6, lane = tid & 63;
  const int wr = wid >> 1, wc = wid & 1;
  const int q = lane >> 4, r16 = lane & 15;
  const int m0 = blockIdx.y * (32*MT);
  const int n0 = blockIdx.x * (32*NT);
  f4 acc[MT][NT];
  #pragma unroll
  for (int i = 0; i < MT; ++i)
    #pragma unroll
    for (int j = 0; j < NT; ++j) { f4 z = {0.f,0.f,0.f,0.f}; acc[i][j] = z; }

  const int kc = K >> 5;
  for (int k = 0; k < kc; ++k) {
    const int k0 = k*32 + q*8;
    #pragma unroll
    for (int t = wid; t < AT; t += 4)
      GL2L(A + (size_t)(m0 + t*16 + r16)*lda + k0, As + t*512);
    #pragma unroll
    for (int t = wid; t < BT; t += 4)
      GL2L(W + (size_t)(n0 + t*16 + r16)*ldw + k0, Bs + t*512);
    __syncthreads();
    bf8 af[MT], bfr[NT];
    #pragma unroll
    for (int i = 0; i < MT; ++i)
      af[i] = *(const bf8*)(As + ((size_t)((wr*MT+i)*64 + lane))*8);
    #pragma unroll
    for (int j = 0; j < NT; ++j)
      bfr[j] = *(const bf8*)(Bs + ((size_t)((wc*NT+j)*64 + lane))*8);
    #pragma unroll
    for (int i = 0; i < MT; ++i)
      #pragma unroll
      for (int j = 0; j < NT; ++j)
        acc[i][j] = __builtin_amdgcn_mfma_f32_16x16x32_bf16(af[i], bfr[j], acc[i][j], 0, 0, 0);
    __syncthreads();
  }

  if constexpr (EPI == 0) {
    #pragma unroll
    for (int i = 0; i < MT; ++i) {
      const int row = m0 + (wr*MT+i)*16 + q*4;
      #pragma unroll
      for (int j = 0; j < NT; ++j) {
        const int col = n0 + (wc*NT+j)*16 + r16;
        #pragma unroll
        for (int r = 0; r < 4; ++r)
          Cf[(size_t)(row+r)*ldc + col] = acc[i][j][r];
      }
    }
  } else if constexpr (EPI == 1) {
    const float bns = rsqrtf(1.0f + 1e-5f);
    #pragma unroll
    for (int j = 0; j < NT; ++j) {
      const int col = n0 + (wc*NT+j)*16 + r16;
      const float b1 = p0[col], sg = p1[col]*bns, b2 = p2[col];
      #pragma unroll
      for (int i = 0; i < MT; ++i) {
        const int row = m0 + (wr*MT+i)*16 + q*4;
        #pragma unroll
        for (int r = 0; r < 4; ++r) {
          float v = fmaxf(fmaf(acc[i][j][r] + b1, sg, b2), 0.0f);
          Cb[(size_t)(row+r)*ldc + col] = f2bf(v);
        }
      }
    }
  } else {
    #pragma unroll
    for (int j = 0; j < NT; ++j) {
      const int col = n0 + (wc*NT+j)*16 + r16;
      float tm[4];
      #pragma unroll
      for (int i = 0; i < 4; ++i) {
        float t = fmaxf(fmaxf(acc[i][j][0], acc[i][j][1]), fmaxf(acc[i][j][2], acc[i][j][3]));
        t = fmaxf(t, __shfl_xor(t, 16));
        t = fmaxf(t, __shfl_xor(t, 32));
        tm[i] = t;
      }
      const float bias = p0[col];
      if (lane < 16) {
        const int g0 = (m0 >> 5) + wr*2;
        Cf[(size_t)g0*ldc + col]     = fmaxf(tm[0], tm[1]) + bias;
        Cf[(size_t)(g0+1)*ldc + col] = fmaxf(tm[2], tm[3]) + bias;
      }
    }
  }
}

// ---------------------------------------------------------------- pos MLP (+ add into h)
__global__ __launch_bounds__(128) void pos_kernel(
    const float* __restrict__ centerb,
    const float* __restrict__ pw1, const float* __restrict__ pb1,
    const float* __restrict__ pw2, const float* __restrict__ pb2,
    float* __restrict__ h) {
  const int bg = blockIdx.x;
  const int tid = threadIdx.x;
  __shared__ float t1[128];
  const float cx = centerb[bg*3+0], cy = centerb[bg*3+1], cz = centerb[bg*3+2];
  {
    const int c = tid;
    float v = cx*pw1[c*3+0] + cy*pw1[c*3+1] + cz*pw1[c*3+2] + pb1[c];
    float u = 0.7978845608028654f * (v + 0.044715f*v*v*v);
    t1[c] = 0.5f*v*(1.0f + tanhf(u));
  }
  __syncthreads();
  for (int e = tid; e < PDM; e += 128) {
    float acc = pb2[e];
    const float4* w = (const float4*)(pw2 + (size_t)e*128);
    const float4* a = (const float4*)t1;
    for (int k4 = 0; k4 < 32; ++k4) {
      float4 wv = w[k4], av = a[k4];
      acc = fmaf(av.x, wv.x, fmaf(av.y, wv.y, fmaf(av.z, wv.z, fmaf(av.w, wv.w, acc))));
    }
    h[(size_t)bg*PDM + e] += acc;
  }
}

// ---------------------------------------------------------------- prenorm -> bf16
__global__ __launch_bounds__(128) void prenorm_kernel(
    const float* __restrict__ h, float* __restrict__ res,
    const float* __restrict__ w, const float* __restrict__ bb,
    ushort_t* __restrict__ xo, int first) {
  const int row = blockIdx.x;
  const int tid = threadIdx.x;
  __shared__ float s1[2], s2[2];
  float v[3];
  #pragma unroll
  for (int i = 0; i < 3; ++i) {
    int j = tid + i*128;
    float r = h[(size_t)row*PDM + j];
    if (!first) r += res[(size_t)row*PDM + j];
    res[(size_t)row*PDM + j] = r;
    v[i] = r;
  }
  float ss = v[0] + v[1] + v[2];
  #pragma unroll
  for (int off = 1; off < 64; off <<= 1) ss += __shfl_xor(ss, off);
  if ((tid & 63) == 0) s1[tid>>6] = ss;
  __syncthreads();
  const float mu = (s1[0] + s1[1]) * (1.0f/384.0f);
  float qq = 0.f;
  #pragma unroll
  for (int i = 0; i < 3; ++i) { float d = v[i] - mu; qq += d*d; }
  #pragma unroll
  for (int off = 1; off < 64; off <<= 1) qq += __shfl_xor(qq, off);
  if ((tid & 63) == 0) s2[tid>>6] = qq;
  __syncthreads();
  const float rs = rsqrtf((s2[0] + s2[1]) * (1.0f/384.0f) + 1e-5f);
  #pragma unroll
  for (int i = 0; i < 3; ++i) {
    int j = tid + i*128;
    xo[(size_t)row*PDM + j] = f2bf((v[i] - mu) * rs * w[j] + bb[j]);
  }
}

// ---------------------------------------------------------------- final LN -> d_out
__global__ __launch_bounds__(128) void final_kernel(
    const float* __restrict__ h, const float* __restrict__ res,
    const float* __restrict__ w, const float* __restrict__ bb,
    float* __restrict__ out) {
  const int row = blockIdx.x;
  const int tid = threadIdx.x;
  __shared__ float s1[2], s2[2];
  float v[3];
  #pragma unroll
  for (int i = 0; i < 3; ++i) {
    int j = tid + i*128;
    v[i] = h[(size_t)row*PDM + j] + res[(size_t)row*PDM + j];
  }
  float ss = v[0] + v[1] + v[2];
  #pragma unroll
  for (int off = 1; off < 64; off <<= 1) ss += __shfl_xor(ss, off);
  if ((tid & 63) == 0) s1[tid>>6] = ss;
  __syncthreads();
  const float mu = (s1[0] + s1[1]) * (1.0f/384.0f);
  float qq = 0.f;
  #pragma unroll
  for (int i = 0; i < 3; ++i) { float d = v[i] - mu; qq += d*d; }
  #pragma unroll
  for (int off = 1; off < 64; off <<= 1) qq += __shfl_xor(qq, off);
  if ((tid & 63) == 0) s2[tid>>6] = qq;
  __syncthreads();
  const float rs = rsqrtf((s2[0] + s2[1]) * (1.0f/384.0f) + 1e-5f);
  #pragma unroll
  for (int i = 0; i < 3; ++i) {
    int j = tid + i*128;
    out[(size_t)row*PDM + j] = (v[i] - mu) * rs * w[j] + bb[j];
  }
}

// ---------------------------------------------------------------- fused conv+silu + xp + dt (one block per row)
__global__ __launch_bounds__(256) void cxd_kernel(
    const float* __restrict__ xz,
    const float* __restrict__ cw, const float* __restrict__ cb,
    const float* __restrict__ xpw,
    const float* __restrict__ dtwT, const float* __restrict__ dtbias,
    float* __restrict__ xin, float* __restrict__ dbl, float* __restrict__ dtg) {
  const int row = blockIdx.x;
  const int tid = threadIdx.x;
  const int wid = tid >> 6, lane = tid & 63;
  const int l = row & 127;
  const int bb = row - l;
  __shared__ float xin_s[PDI];
  __shared__ float dbl_s[56];
  #pragma unroll
  for (int i = 0; i < 3; ++i) {
    const int d = tid + i*256;
    float acc = cb[d];
    #pragma unroll
    for (int k = 0; k < 4; ++k) {
      int ll = l + k - 3;
      if (ll >= 0) acc = fmaf(xz[(size_t)(bb+ll)*1536 + d], cw[d*4+k], acc);
    }
    float s = 1.0f / (1.0f + expf(-acc));
    float v = acc * s;
    xin_s[d] = v;
    xin[(size_t)row*PDI + d] = v;
  }
  __syncthreads();
  for (int e = wid; e < 56; e += 4) {
    const float* wr = xpw + (size_t)e*PDI;
    float a = 0.f;
    #pragma unroll
    for (int t = 0; t < 12; ++t) {
      int k = lane + t*64;
      a = fmaf(xin_s[k], wr[k], a);
    }
    #pragma unroll
    for (int off = 1; off < 64; off <<= 1) a += __shfl_xor(a, off);
    if (lane == 0) { dbl_s[e] = a; dbl[(size_t)row*56 + e] = a; }
  }
  __syncthreads();
  #pragma unroll
  for (int i = 0; i < 3; ++i) {
    const int d = tid + i*256;
    float acc = dtbias[d];
    #pragma unroll
    for (int r = 0; r < 24; ++r) acc = fmaf(dbl_s[r], dtwT[r*768 + d], acc);
    dtg[(size_t)row*PDI + d] = log1pf(expf(-fabsf(acc))) + fmaxf(acc, 0.0f);
  }
}

// ---------------------------------------------------------------- selective scan + gate -> bf16
__global__ __launch_bounds__(256) void scan_kernel(const float* __restrict__ dt,
                                                   const float* __restrict__ xin,
                                                   const float* __restrict__ dbl,
                                                   const float* __restrict__ alog,
                                                   const float* __restrict__ dp,
                                                   const float* __restrict__ xz,
                                                   ushort_t* __restrict__ yb) {
  const int s = threadIdx.x & 15;
  const int dl = threadIdx.x >> 4;
  const int d = blockIdx.x*16 + dl;
  const int b = blockIdx.y;
  const float A = -expf(alog[d*16 + s]);
  const float Dv = dp[d];
  float h = 0.f;
  for (int l = 0; l < 128; ++l) {
    const int ro = b*128 + l;
    float dtv = dt[(size_t)ro*PDI + d];
    float xv  = xin[(size_t)ro*PDI + d];
    float Bv  = dbl[(size_t)ro*56 + 24 + s];
    float Cv  = dbl[(size_t)ro*56 + 40 + s];
    float dA = expf(dtv * A);
    h = fmaf(dA, h, dtv * xv * Bv);
    float p = h * Cv;
    p += __shfl_xor(p, 1);
    p += __shfl_xor(p, 2);
    p += __shfl_xor(p, 4);
    p += __shfl_xor(p, 8);
    if (s == 0) {
      float z = xz[(size_t)ro*1536 + 768 + d];
      float sg = 1.0f / (1.0f + expf(-z));
      yb[(size_t)ro*PDI + d] = f2bf(fmaf(Dv, xv, p) * z * sg);
    }
  }
}

// ---------------------------------------------------------------- host
extern "C" void kernel_launch(void* const* d_in, const int* in_sizes, int n_in,
                              void* d_out, int out_size, void* d_ws, size_t ws_size,
                              hipStream_t stream) {
  const float* xyz    = (const float*)d_in[0];
  const float* e1w1   = (const float*)d_in[1];
  const float* e1b1   = (const float*)d_in[2];
  const float* bn1g   = (const float*)d_in[3];
  const float* bn1b   = (const float*)d_in[4];
  const float* e1w2   = (const float*)d_in[5];
  const float* e1b2   = (const float*)d_in[6];
  const float* e2w1   = (const float*)d_in[7];
  const float* e2b1   = (const float*)d_in[8];
  const float* bn2g   = (const float*)d_in[9];
  const float* bn2b   = (const float*)d_in[10];
  const float* e2w2   = (const float*)d_in[11];
  const float* e2b2   = (const float*)d_in[12];
  const float* pw1    = (const float*)d_in[13];
  const float* pb1    = (const float*)d_in[14];
  const float* pw2    = (const float*)d_in[15];
  const float* pb2    = (const float*)d_in[16];
  const float* in_w   = (const float*)d_in[17];
  const float* conv_w = (const float*)d_in[18];
  const float* conv_b = (const float*)d_in[19];
  const float* xp_w   = (const float*)d_in[20];
  const float* dt_w   = (const float*)d_in[21];
  const float* dt_b   = (const float*)d_in[22];
  const float* A_log  = (const float*)d_in[23];
  const float* Dp     = (const float*)d_in[24];
  const float* out_w  = (const float*)d_in[25];
  const float* lnw    = (const float*)d_in[26];
  const float* lnb    = (const float*)d_in[27];
  const float* fnw    = (const float*)d_in[28];
  const float* fnb    = (const float*)d_in[29];

  char* ws = (char*)d_ws;
  size_t off = 0;
  auto alloc = [&](size_t bytes) { void* p = ws + off; off += (bytes + 255) & ~(size_t)255; return p; };
  int*      cidx    = (int*)     alloc(PB*PG*4);
  float*    centerb = (float*)   alloc(ROWS*3*4);
  float*    nbx     = (float*)   alloc(ROWS*PM*3*4);
  ushort_t* concat  = (ushort_t*)alloc((size_t)ROWS*PM*512*2);   // 64 MB
  ushort_t* f3      = (ushort_t*)alloc((size_t)ROWS*PM*512*2);   // 64 MB
  float*    hbuf    = (float*)   alloc((size_t)ROWS*PDM*4);
  float*    resid   = (float*)   alloc((size_t)ROWS*PDM*4);
  ushort_t* xlnb    = (ushort_t*)alloc((size_t)ROWS*PDM*2);
  float*    xz      = (float*)   alloc((size_t)ROWS*1536*4);
  float*    xin     = (float*)   alloc((size_t)ROWS*PDI*4);
  float*    dbl     = (float*)   alloc((size_t)ROWS*56*4);
  float*    dtg     = (float*)   alloc((size_t)ROWS*PDI*4);
  ushort_t* ybufb   = (ushort_t*)alloc((size_t)ROWS*PDI*2);
  ushort_t* wb      = (ushort_t*)alloc((size_t)CV_TOT*2);
  float*    dtwT    = (float*)   alloc((size_t)12*24*768*4);

  ushort_t* e1w2b  = wb;
  ushort_t* e2w1b  = wb + CV_O1;
  ushort_t* e2w2b  = wb + CV_O2;
  ushort_t* in_wb  = wb + CV_O3;
  ushort_t* out_wb = wb + CV_O4;

  cvt_all_kernel<<<(CV_TOT+255)/256, 256, 0, stream>>>(e1w2, e2w1, e2w2, in_w, out_w, wb);
  dtw_t_kernel<<<(12*768*24+255)/256, 256, 0, stream>>>(dt_w, dtwT);

  fps_kernel<<<PB, 64, 0, stream>>>(xyz, cidx);
  knn_kernel<<<ROWS, 64, 0, stream>>>(xyz, cidx, nbx, centerb);
  embed1_kernel<<<ROWS, 256, 0, stream>>>(nbx, e1w1, e1b1, bn1g, bn1b, e1w2b, e1b2, concat);

  // stage C: (65536,512)@(512,512)^T, bn+relu -> bf16 f3
  mfma_gemm<4,4,1><<<dim3(4, 512), 256, 0, stream>>>(
      concat, 512, e2w1b, 512, nullptr, f3, 512, 512, e2b1, bn2g, bn2b);
  // stage D: (65536,512)@(384,512)^T, +bias, group-max -> tokens (hbuf)
  mfma_gemm<4,4,2><<<dim3(3, 512), 256, 0, stream>>>(
      f3, 512, e2w2b, 512, hbuf, nullptr, PDM, 512, e2b2, nullptr, nullptr);

  pos_kernel<<<ROWS, 128, 0, stream>>>(centerb, pw1, pb1, pw2, pb2, hbuf);

  for (int i = 0; i < 12; ++i) {
    prenorm_kernel<<<ROWS, 128, 0, stream>>>(hbuf, resid, lnw + i*384, lnb + i*384, xlnb, (i == 0) ? 1 : 0);
    mfma_gemm<4,4,0><<<dim3(12, 16), 256, 0, stream>>>(
        xlnb, PDM, in_wb + (size_t)i*1536*384, PDM, xz, nullptr, 1536, PDM,
        nullptr, nullptr, nullptr);
    cxd_kernel<<<ROWS, 256, 0, stream>>>(
        xz, conv_w + (size_t)i*768*4, conv_b + (size_t)i*768,
        xp_w + (size_t)i*56*768, dtwT + (size_t)i*24*768, dt_b + (size_t)i*768,
        xin, dbl, dtg);
    scan_kernel<<<dim3(48, PB), 256, 0, stream>>>(
        dtg, xin, dbl, A_log + (size_t)i*768*16, Dp + (size_t)i*768, xz, ybufb);
    mfma_gemm<2,2,0><<<dim3(6, 32), 256, 0, stream>>>(
        ybufb, PDI, out_wb + (size_t)i*384*768, PDI, hbuf, nullptr, PDM, PDI,
        nullptr, nullptr, nullptr);
  }

  final_kernel<<<ROWS, 128, 0, stream>>>(hbuf, resid, fnw, fnb, (float*)d_out);
}

// Round 4
// 1942.102 us; speedup vs baseline: 1.3581x; 1.3581x over previous
//
#include <hip/hip_runtime.h>
#include <hip/hip_bf16.h>
#include <math.h>

#define PN   2048
#define PB   16
#define PG   128
#define PM   32
#define PDM  384
#define PDI  768
#define ROWS 2048   // B*G == B*L

typedef unsigned short ushort_t;
typedef __attribute__((ext_vector_type(8))) short bf8;
typedef __attribute__((ext_vector_type(4))) float f4;

__device__ __forceinline__ ushort_t f2bf(float x) {
  unsigned int u = __float_as_uint(x);
  unsigned int r = (u + 0x7FFFu + ((u >> 16) & 1u)) >> 16;
  return (ushort_t)r;
}

#define GL2L(gp, lp) __builtin_amdgcn_global_load_lds((const __attribute__((address_space(1))) void*)(gp), (__attribute__((address_space(3))) void*)(lp), 16, 0, 0)

// ---------------------------------------------------------------- prep: all weight conversions in ONE launch
// bf16 regions: e1w2(32768) e2w1(262144) e2w2(196608) in_w(7077888) out_w(3538944)
#define CV_O1 32768
#define CV_O2 294912
#define CV_O3 491520
#define CV_O4 7569408
#define CV_TOT 11108352
#define DTWT_TOT (12*768*24)       // 221184
#define XPWT_TOT (12*192*64*4)     // 589824  layout [layer][r4][e(64)][j(4)]
#define PREP_TOT (CV_TOT + DTWT_TOT + XPWT_TOT)
__global__ __launch_bounds__(256) void prep_kernel(
    const float* __restrict__ e1w2, const float* __restrict__ e2w1,
    const float* __restrict__ e2w2, const float* __restrict__ in_w,
    const float* __restrict__ out_w, const float* __restrict__ dt_w,
    const float* __restrict__ xp_w,
    ushort_t* __restrict__ wb, float* __restrict__ dtwT,
    float* __restrict__ xpwT) {
  int i = blockIdx.x*256 + threadIdx.x;
  if (i >= PREP_TOT) return;
  if (i < CV_TOT) {
    const float* s; int off;
    if      (i < CV_O1) { s = e1w2;  off = 0; }
    else if (i < CV_O2) { s = e2w1;  off = CV_O1; }
    else if (i < CV_O3) { s = e2w2;  off = CV_O2; }
    else if (i < CV_O4) { s = in_w;  off = CV_O3; }
    else                { s = out_w; off = CV_O4; }
    wb[i] = f2bf(s[i - off]);
  } else if (i < CV_TOT + DTWT_TOT) {
    int j = i - CV_TOT;
    int layer = j / (768*24);
    int rem = j - layer*768*24;
    int d = rem / 24, r = rem - d*24;
    dtwT[layer*24*768 + r*768 + d] = dt_w[j];
  } else {
    int j = i - CV_TOT - DTWT_TOT;
    int layer = j / 49152;
    int rem = j - layer*49152;
    int r4 = rem >> 8;
    int rem2 = rem & 255;
    int e = rem2 >> 2, jj = rem2 & 3;
    xpwT[j] = (e < 56) ? xp_w[(size_t)layer*56*768 + (size_t)e*768 + r4*4 + jj] : 0.f;
  }
}

// ---------------------------------------------------------------- FPS: 4 waves per batch, 8 pts/lane
__global__ __launch_bounds__(256) void fps_kernel(const float* __restrict__ xyz,
                                                  int* __restrict__ cidx) {
  const int b = blockIdx.x;
  const int tid = threadIdx.x;
  const int wave = tid >> 6, lane = tid & 63;
  __shared__ float pts[PN*3];
  __shared__ float wvv[2][4]; __shared__ int wii[2][4];
  const float* base = xyz + (size_t)b * PN * 3;
  for (int t = tid; t < PN*3; t += 256) pts[t] = base[t];
  __syncthreads();
  float px[8], py[8], pz[8], dmin[8];
  #pragma unroll
  for (int j = 0; j < 8; ++j) {
    int idx = j*256 + tid;
    px[j] = pts[idx*3+0]; py[j] = pts[idx*3+1]; pz[j] = pts[idx*3+2];
    dmin[j] = 1e10f;
  }
  int cur = 0;
  for (int g = 0; g < PG; ++g) {
    if (tid == 0) cidx[b*PG + g] = cur;
    const float cx = pts[cur*3+0], cy = pts[cur*3+1], cz = pts[cur*3+2];
    float bestv = -1.0f; int besti = 0;
    #pragma unroll
    for (int j = 0; j < 8; ++j) {
      float dx = __fsub_rn(px[j], cx);
      float dy = __fsub_rn(py[j], cy);
      float dz = __fsub_rn(pz[j], cz);
      float dd = __fadd_rn(__fadd_rn(__fmul_rn(dx,dx), __fmul_rn(dy,dy)), __fmul_rn(dz,dz));
      float dm = fminf(dmin[j], dd);
      dmin[j] = dm;
      if (dm > bestv) { bestv = dm; besti = j*256 + tid; }   // ascending idx -> lowest on tie
    }
    #pragma unroll
    for (int off = 1; off < 64; off <<= 1) {
      float ov = __shfl_xor(bestv, off);
      int   oi = __shfl_xor(besti, off);
      if (ov > bestv || (ov == bestv && oi < besti)) { bestv = ov; besti = oi; }
    }
    const int par = g & 1;
    if (lane == 0) { wvv[par][wave] = bestv; wii[par][wave] = besti; }
    __syncthreads();
    float v = wvv[par][0]; int bi = wii[par][0];
    #pragma unroll
    for (int w = 1; w < 4; ++w)
      if (wvv[par][w] > v || (wvv[par][w] == v && wii[par][w] < bi)) { v = wvv[par][w]; bi = wii[par][w]; }
    cur = bi;
  }
}

// ---------------------------------------------------------------- kNN: one wave per group, d2 in regs
__global__ __launch_bounds__(64) void knn_kernel(const float* __restrict__ xyz,
                                                 const int* __restrict__ cidx,
                                                 float* __restrict__ nbx,
                                                 float* __restrict__ centerb) {
  const int bg = blockIdx.x;
  const int b = bg >> 7;
  const int lane = threadIdx.x;
  const float* base = xyz + (size_t)b * PN * 3;
  const int ci = cidx[bg];
  const float cx = base[ci*3+0], cy = base[ci*3+1], cz = base[ci*3+2];
  if (lane == 0) { centerb[bg*3+0]=cx; centerb[bg*3+1]=cy; centerb[bg*3+2]=cz; }
  float d2[32];
  #pragma unroll
  for (int j = 0; j < 32; ++j) {
    int idx = j*64 + lane;
    float dx = __fsub_rn(cx, base[idx*3+0]);
    float dy = __fsub_rn(cy, base[idx*3+1]);
    float dz = __fsub_rn(cz, base[idx*3+2]);
    d2[j] = __fadd_rn(__fadd_rn(__fmul_rn(dx,dx), __fmul_rn(dy,dy)), __fmul_rn(dz,dz));
  }
  for (int m = 0; m < PM; ++m) {
    float bestv = 1e38f; int besti = 0x7fffffff;
    #pragma unroll
    for (int j = 0; j < 32; ++j) {
      int idx = j*64 + lane;
      if (d2[j] < bestv) { bestv = d2[j]; besti = idx; }
    }
    #pragma unroll
    for (int off = 1; off < 64; off <<= 1) {
      float ov = __shfl_xor(bestv, off);
      int   oi = __shfl_xor(besti, off);
      if (ov < bestv || (ov == bestv && oi < besti)) { bestv = ov; besti = oi; }
    }
    const int k = __builtin_amdgcn_readfirstlane(besti);
    const int jwin = k >> 6, owner = k & 63;
    #pragma unroll
    for (int j = 0; j < 32; ++j)
      if (j == jwin && lane == owner) d2[j] = 1e38f;
    if (lane == 0) {
      nbx[(bg*PM + m)*3 + 0] = base[k*3+0] - cx;
      nbx[(bg*PM + m)*3 + 1] = base[k*3+1] - cy;
      nbx[(bg*PM + m)*3 + 2] = base[k*3+2] - cz;
    }
  }
}

// ---------------------------------------------------------------- embed stage A (fp32 VALU) + stage B (MFMA) -> concat bf16
__global__ __launch_bounds__(256) void embed1_kernel(
    const float* __restrict__ nbx,
    const float* __restrict__ e1w1, const float* __restrict__ e1b1,
    const float* __restrict__ bn1g, const float* __restrict__ bn1b,
    const ushort_t* __restrict__ e1w2b, const float* __restrict__ e1b2,
    ushort_t* __restrict__ concat) {
  const int bg = blockIdx.x;
  const int tid = threadIdx.x;
  const int wid = tid >> 6, lane = tid & 63;
  const int q = lane >> 4, r16 = lane & 15;
  __shared__ float xs[PM*3];
  __shared__ __align__(16) ushort_t Af[4*2*64*8];
  __shared__ __align__(16) ushort_t Bs[16*64*8];
  if (tid < PM*3) xs[tid] = nbx[bg*PM*3 + tid];
  __syncthreads();
  const float bnscale = rsqrtf(1.0f + 1e-5f);
  #pragma unroll
  for (int it = 0; it < 16; ++it) {
    int id = tid + it*256;
    int m = id >> 7, c = id & 127;
    float v = xs[m*3+0]*e1w1[c*3+0] + xs[m*3+1]*e1w1[c*3+1] + xs[m*3+2]*e1w1[c*3+2] + e1b1[c];
    v = v * (bn1g[c]*bnscale) + bn1b[c];
    v = fmaxf(v, 0.0f);
    int kc = c >> 5, cc = c & 31, qq = cc >> 3, j = cc & 7;
    int t = m >> 4, r = m & 15;
    Af[((kc*2 + t)*64 + qq*16 + r)*8 + j] = f2bf(v);
  }
  f4 acc[2][4];
  #pragma unroll
  for (int t = 0; t < 2; ++t)
    #pragma unroll
    for (int jj = 0; jj < 4; ++jj) { f4 z = {0.f,0.f,0.f,0.f}; acc[t][jj] = z; }
  for (int kc = 0; kc < 4; ++kc) {
    #pragma unroll
    for (int u = wid; u < 16; u += 4)
      GL2L(e1w2b + (size_t)(u*16 + r16)*128 + kc*32 + q*8, Bs + u*512);
    __syncthreads();
    bf8 a0 = *(const bf8*)(Af + ((size_t)((kc*2+0)*64 + lane))*8);
    bf8 a1 = *(const bf8*)(Af + ((size_t)((kc*2+1)*64 + lane))*8);
    #pragma unroll
    for (int jj = 0; jj < 4; ++jj) {
      bf8 bv = *(const bf8*)(Bs + ((size_t)((wid*4+jj)*64 + lane))*8);
      acc[0][jj] = __builtin_amdgcn_mfma_f32_16x16x32_bf16(a0, bv, acc[0][jj], 0, 0, 0);
      acc[1][jj] = __builtin_amdgcn_mfma_f32_16x16x32_bf16(a1, bv, acc[1][jj], 0, 0, 0);
    }
    __syncthreads();
  }
  #pragma unroll
  for (int jj = 0; jj < 4; ++jj) {
    const int n = (wid*4+jj)*16 + r16;
    const float bias = e1b2[n];
    float v0[4], v1[4];
    float cm = -1e30f;
    #pragma unroll
    for (int rr = 0; rr < 4; ++rr) {
      v0[rr] = acc[0][jj][rr] + bias;
      v1[rr] = acc[1][jj][rr] + bias;
      cm = fmaxf(cm, fmaxf(v0[rr], v1[rr]));
    }
    cm = fmaxf(cm, __shfl_xor(cm, 16));
    cm = fmaxf(cm, __shfl_xor(cm, 32));
    ushort_t mxb = f2bf(cm);
    #pragma unroll
    for (int rr = 0; rr < 4; ++rr) {
      size_t base0 = ((size_t)bg*32 + q*4 + rr)*512;
      size_t base1 = ((size_t)bg*32 + 16 + q*4 + rr)*512;
      concat[base0 + 256 + n] = f2bf(v0[rr]);
      concat[base1 + 256 + n] = f2bf(v1[rr]);
      concat[base0 + n] = mxb;
      concat[base1 + n] = mxb;
    }
  }
}

// ---------------------------------------------------------------- bf16 MFMA GEMM, BK=64 (2 chunks per barrier pair)
template<int MT, int NT, int EPI>
__global__ __launch_bounds__(256) void mfma_gemm(
    const ushort_t* __restrict__ A, int lda,
    const ushort_t* __restrict__ W, int ldw,
    float* __restrict__ Cf, ushort_t* __restrict__ Cb, int ldc, int K,
    const float* __restrict__ p0, const float* __restrict__ p1,
    const float* __restrict__ p2) {
  static_assert(EPI != 2 || MT == 4, "groupmax needs MT=4");
  constexpr int AT = 2*MT, BT = 2*NT;
  __shared__ __align__(16) ushort_t As[2*AT*512];
  __shared__ __align__(16) ushort_t Bs[2*BT*512];
  const int tid = threadIdx.x;
  const int wid = tid >> 6, lane = tid & 63;
  const int wr = wid >> 1, wc = wid & 1;
  const int q = lane >> 4, r16 = lane & 15;
  const int m0 = blockIdx.y * (32*MT);
  const int n0 = blockIdx.x * (32*NT);
  f4 acc[MT][NT];
  #pragma unroll
  for (int i = 0; i < MT; ++i)
    #pragma unroll
    for (int j = 0; j < NT; ++j) { f4 z = {0.f,0.f,0.f,0.f}; acc[i][j] = z; }

  for (int k0 = 0; k0 < K; k0 += 64) {
    #pragma unroll
    for (int c = 0; c < 2; ++c) {
      const int kk = k0 + c*32 + q*8;
      #pragma unroll
      for (int t = wid; t < AT; t += 4)
        GL2L(A + (size_t)(m0 + t*16 + r16)*lda + kk, As + (c*AT + t)*512);
      #pragma unroll
      for (int t = wid; t < BT; t += 4)
        GL2L(W + (size_t)(n0 + t*16 + r16)*ldw + kk, Bs + (c*BT + t)*512);
    }
    __syncthreads();
    #pragma unroll
    for (int c = 0; c < 2; ++c) {
      bf8 af[MT], bfr[NT];
      #pragma unroll
      for (int i = 0; i < MT; ++i)
        af[i] = *(const bf8*)(As + ((size_t)(c*AT + wr*MT+i)*64 + lane)*8);
      #pragma unroll
      for (int j = 0; j < NT; ++j)
        bfr[j] = *(const bf8*)(Bs + ((size_t)(c*BT + wc*NT+j)*64 + lane)*8);
      #pragma unroll
      for (int i = 0; i < MT; ++i)
        #pragma unroll
        for (int j = 0; j < NT; ++j)
          acc[i][j] = __builtin_amdgcn_mfma_f32_16x16x32_bf16(af[i], bfr[j], acc[i][j], 0, 0, 0);
    }
    __syncthreads();
  }

  if constexpr (EPI == 0) {
    #pragma unroll
    for (int i = 0; i < MT; ++i) {
      const int row = m0 + (wr*MT+i)*16 + q*4;
      #pragma unroll
      for (int j = 0; j < NT; ++j) {
        const int col = n0 + (wc*NT+j)*16 + r16;
        #pragma unroll
        for (int r = 0; r < 4; ++r)
          Cf[(size_t)(row+r)*ldc + col] = acc[i][j][r];
      }
    }
  } else if constexpr (EPI == 1) {
    const float bns = rsqrtf(1.0f + 1e-5f);
    #pragma unroll
    for (int j = 0; j < NT; ++j) {
      const int col = n0 + (wc*NT+j)*16 + r16;
      const float b1 = p0[col], sg = p1[col]*bns, b2 = p2[col];
      #pragma unroll
      for (int i = 0; i < MT; ++i) {
        const int row = m0 + (wr*MT+i)*16 + q*4;
        #pragma unroll
        for (int r = 0; r < 4; ++r) {
          float v = fmaxf(fmaf(acc[i][j][r] + b1, sg, b2), 0.0f);
          Cb[(size_t)(row+r)*ldc + col] = f2bf(v);
        }
      }
    }
  } else {
    #pragma unroll
    for (int j = 0; j < NT; ++j) {
      const int col = n0 + (wc*NT+j)*16 + r16;
      float tm[4];
      #pragma unroll
      for (int i = 0; i < 4; ++i) {
        float t = fmaxf(fmaxf(acc[i][j][0], acc[i][j][1]), fmaxf(acc[i][j][2], acc[i][j][3]));
        t = fmaxf(t, __shfl_xor(t, 16));
        t = fmaxf(t, __shfl_xor(t, 32));
        tm[i] = t;
      }
      const float bias = p0[col];
      if (lane < 16) {
        const int g0 = (m0 >> 5) + wr*2;
        Cf[(size_t)g0*ldc + col]     = fmaxf(tm[0], tm[1]) + bias;
        Cf[(size_t)(g0+1)*ldc + col] = fmaxf(tm[2], tm[3]) + bias;
      }
    }
  }
}

// ---------------------------------------------------------------- pos MLP (+ add into h)
__global__ __launch_bounds__(128) void pos_kernel(
    const float* __restrict__ centerb,
    const float* __restrict__ pw1, const float* __restrict__ pb1,
    const float* __restrict__ pw2, const float* __restrict__ pb2,
    float* __restrict__ h) {
  const int bg = blockIdx.x;
  const int tid = threadIdx.x;
  __shared__ float t1[128];
  const float cx = centerb[bg*3+0], cy = centerb[bg*3+1], cz = centerb[bg*3+2];
  {
    const int c = tid;
    float v = cx*pw1[c*3+0] + cy*pw1[c*3+1] + cz*pw1[c*3+2] + pb1[c];
    float u = 0.7978845608028654f * (v + 0.044715f*v*v*v);
    t1[c] = 0.5f*v*(1.0f + tanhf(u));
  }
  __syncthreads();
  for (int e = tid; e < PDM; e += 128) {
    float acc = pb2[e];
    const float4* w = (const float4*)(pw2 + (size_t)e*128);
    const float4* a = (const float4*)t1;
    for (int k4 = 0; k4 < 32; ++k4) {
      float4 wv = w[k4], av = a[k4];
      acc = fmaf(av.x, wv.x, fmaf(av.y, wv.y, fmaf(av.z, wv.z, fmaf(av.w, wv.w, acc))));
    }
    h[(size_t)bg*PDM + e] += acc;
  }
}

// ---------------------------------------------------------------- prenorm -> bf16
__global__ __launch_bounds__(128) void prenorm_kernel(
    const float* __restrict__ h, float* __restrict__ res,
    const float* __restrict__ w, const float* __restrict__ bb,
    ushort_t* __restrict__ xo, int first) {
  const int row = blockIdx.x;
  const int tid = threadIdx.x;
  __shared__ float s1[2], s2[2];
  float v[3];
  #pragma unroll
  for (int i = 0; i < 3; ++i) {
    int j = tid + i*128;
    float r = h[(size_t)row*PDM + j];
    if (!first) r += res[(size_t)row*PDM + j];
    res[(size_t)row*PDM + j] = r;
    v[i] = r;
  }
  float ss = v[0] + v[1] + v[2];
  #pragma unroll
  for (int off = 1; off < 64; off <<= 1) ss += __shfl_xor(ss, off);
  if ((tid & 63) == 0) s1[tid>>6] = ss;
  __syncthreads();
  const float mu = (s1[0] + s1[1]) * (1.0f/384.0f);
  float qq = 0.f;
  #pragma unroll
  for (int i = 0; i < 3; ++i) { float d = v[i] - mu; qq += d*d; }
  #pragma unroll
  for (int off = 1; off < 64; off <<= 1) qq += __shfl_xor(qq, off);
  if ((tid & 63) == 0) s2[tid>>6] = qq;
  __syncthreads();
  const float rs = rsqrtf((s2[0] + s2[1]) * (1.0f/384.0f) + 1e-5f);
  #pragma unroll
  for (int i = 0; i < 3; ++i) {
    int j = tid + i*128;
    xo[(size_t)row*PDM + j] = f2bf((v[i] - mu) * rs * w[j] + bb[j]);
  }
}

// ---------------------------------------------------------------- final LN -> d_out
__global__ __launch_bounds__(128) void final_kernel(
    const float* __restrict__ h, const float* __restrict__ res,
    const float* __restrict__ w, const float* __restrict__ bb,
    float* __restrict__ out) {
  const int row = blockIdx.x;
  const int tid = threadIdx.x;
  __shared__ float s1[2], s2[2];
  float v[3];
  #pragma unroll
  for (int i = 0; i < 3; ++i) {
    int j = tid + i*128;
    v[i] = h[(size_t)row*PDM + j] + res[(size_t)row*PDM + j];
  }
  float ss = v[0] + v[1] + v[2];
  #pragma unroll
  for (int off = 1; off < 64; off <<= 1) ss += __shfl_xor(ss, off);
  if ((tid & 63) == 0) s1[tid>>6] = ss;
  __syncthreads();
  const float mu = (s1[0] + s1[1]) * (1.0f/384.0f);
  float qq = 0.f;
  #pragma unroll
  for (int i = 0; i < 3; ++i) { float d = v[i] - mu; qq += d*d; }
  #pragma unroll
  for (int off = 1; off < 64; off <<= 1) qq += __shfl_xor(qq, off);
  if ((tid & 63) == 0) s2[tid>>6] = qq;
  __syncthreads();
  const float rs = rsqrtf((s2[0] + s2[1]) * (1.0f/384.0f) + 1e-5f);
  #pragma unroll
  for (int i = 0; i < 3; ++i) {
    int j = tid + i*128;
    out[(size_t)row*PDM + j] = (v[i] - mu) * rs * w[j] + bb[j];
  }
}

// ---------------------------------------------------------------- fused conv+silu + xp (coalesced) + dt
__global__ __launch_bounds__(256) void cxd_kernel(
    const float* __restrict__ xz,
    const float* __restrict__ cw, const float* __restrict__ cb,
    const float* __restrict__ xpwT,   // [r4(192)][e(64)][4] floats
    const float* __restrict__ dtwT, const float* __restrict__ dtbias,
    float* __restrict__ xin, float* __restrict__ dbl, float* __restrict__ dtg) {
  const int row = blockIdx.x;
  const int tid = threadIdx.x;
  const int wid = tid >> 6, lane = tid & 63;
  const int l = row & 127;
  const int bb = row - l;
  __shared__ float xin_s[PDI];
  __shared__ float part[4][64];
  __shared__ float dbl_s[64];
  #pragma unroll
  for (int i = 0; i < 3; ++i) {
    const int d = tid + i*256;
    float acc = cb[d];
    #pragma unroll
    for (int k = 0; k < 4; ++k) {
      int ll = l + k - 3;
      if (ll >= 0) acc = fmaf(xz[(size_t)(bb+ll)*1536 + d], cw[d*4+k], acc);
    }
    float s = 1.0f / (1.0f + __expf(-acc));
    float v = acc * s;
    xin_s[d] = v;
    xin[(size_t)row*PDI + d] = v;
  }
  __syncthreads();
  {
    const float4* wp = (const float4*)xpwT;
    float a = 0.f;
    const int base_r4 = wid*48;
    for (int t = 0; t < 48; ++t) {
      const int r4 = base_r4 + t;
      float4 w4 = wp[r4*64 + lane];
      float4 x4 = *(const float4*)&xin_s[r4*4];
      a = fmaf(x4.x, w4.x, fmaf(x4.y, w4.y, fmaf(x4.z, w4.z, fmaf(x4.w, w4.w, a))));
    }
    part[wid][lane] = a;
  }
  __syncthreads();
  if (tid < 64) {
    float v = part[0][tid] + part[1][tid] + part[2][tid] + part[3][tid];
    dbl_s[tid] = v;
    if (tid < 56) dbl[(size_t)row*56 + tid] = v;
  }
  __syncthreads();
  #pragma unroll
  for (int i = 0; i < 3; ++i) {
    const int d = tid + i*256;
    float acc = dtbias[d];
    #pragma unroll
    for (int r = 0; r < 24; ++r) acc = fmaf(dbl_s[r], dtwT[r*768 + d], acc);
    dtg[(size_t)row*PDI + d] = log1pf(expf(-fabsf(acc))) + fmaxf(acc, 0.0f);
  }
}

// ---------------------------------------------------------------- selective scan + gate -> bf16 (prefetched)
__global__ __launch_bounds__(256) void scan_kernel(const float* __restrict__ dt,
                                                   const float* __restrict__ xin,
                                                   const float* __restrict__ dbl,
                                                   const float* __restrict__ alog,
                                                   const float* __restrict__ dp,
                                                   const float* __restrict__ xz,
                                                   ushort_t* __restrict__ yb) {
  const int s = threadIdx.x & 15;
  const int dl = threadIdx.x >> 4;
  const int d = blockIdx.x*16 + dl;
  const int b = blockIdx.y;
  const float A = -expf(alog[d*16 + s]);
  const float Dv = dp[d];
  float h = 0.f;
  int ro = b*128;
  float dtv = dt[(size_t)ro*PDI + d];
  float xv  = xin[(size_t)ro*PDI + d];
  float Bv  = dbl[(size_t)ro*56 + 24 + s];
  float Cv  = dbl[(size_t)ro*56 + 40 + s];
  float zv  = xz[(size_t)ro*1536 + 768 + d];
  for (int l = 0; l < 128; ++l) {
    float ndt = 0.f, nxv = 0.f, nBv = 0.f, nCv = 0.f, nz = 0.f;
    const int r2 = ro + 1;
    if (l < 127) {
      ndt = dt[(size_t)r2*PDI + d];
      nxv = xin[(size_t)r2*PDI + d];
      nBv = dbl[(size_t)r2*56 + 24 + s];
      nCv = dbl[(size_t)r2*56 + 40 + s];
      nz  = xz[(size_t)r2*1536 + 768 + d];
    }
    float dA = __expf(dtv * A);
    h = fmaf(dA, h, dtv * xv * Bv);
    float p = h * Cv;
    p += __shfl_xor(p, 1);
    p += __shfl_xor(p, 2);
    p += __shfl_xor(p, 4);
    p += __shfl_xor(p, 8);
    if (s == 0) {
      float sg = 1.0f / (1.0f + __expf(-zv));
      yb[(size_t)ro*PDI + d] = f2bf(fmaf(Dv, xv, p) * zv * sg);
    }
    dtv = ndt; xv = nxv; Bv = nBv; Cv = nCv; zv = nz;
    ro = r2;
  }
}

// ---------------------------------------------------------------- host
extern "C" void kernel_launch(void* const* d_in, const int* in_sizes, int n_in,
                              void* d_out, int out_size, void* d_ws, size_t ws_size,
                              hipStream_t stream) {
  const float* xyz    = (const float*)d_in[0];
  const float* e1w1   = (const float*)d_in[1];
  const float* e1b1   = (const float*)d_in[2];
  const float* bn1g   = (const float*)d_in[3];
  const float* bn1b   = (const float*)d_in[4];
  const float* e1w2   = (const float*)d_in[5];
  const float* e1b2   = (const float*)d_in[6];
  const float* e2w1   = (const float*)d_in[7];
  const float* e2b1   = (const float*)d_in[8];
  const float* bn2g   = (const float*)d_in[9];
  const float* bn2b   = (const float*)d_in[10];
  const float* e2w2   = (const float*)d_in[11];
  const float* e2b2   = (const float*)d_in[12];
  const float* pw1    = (const float*)d_in[13];
  const float* pb1    = (const float*)d_in[14];
  const float* pw2    = (const float*)d_in[15];
  const float* pb2    = (const float*)d_in[16];
  const float* in_w   = (const float*)d_in[17];
  const float* conv_w = (const float*)d_in[18];
  const float* conv_b = (const float*)d_in[19];
  const float* xp_w   = (const float*)d_in[20];
  const float* dt_w   = (const float*)d_in[21];
  const float* dt_b   = (const float*)d_in[22];
  const float* A_log  = (const float*)d_in[23];
  const float* Dp     = (const float*)d_in[24];
  const float* out_w  = (const float*)d_in[25];
  const float* lnw    = (const float*)d_in[26];
  const float* lnb    = (const float*)d_in[27];
  const float* fnw    = (const float*)d_in[28];
  const float* fnb    = (const float*)d_in[29];

  char* ws = (char*)d_ws;
  size_t off = 0;
  auto alloc = [&](size_t bytes) { void* p = ws + off; off += (bytes + 255) & ~(size_t)255; return p; };
  int*      cidx    = (int*)     alloc(PB*PG*4);
  float*    centerb = (float*)   alloc(ROWS*3*4);
  float*    nbx     = (float*)   alloc(ROWS*PM*3*4);
  ushort_t* concat  = (ushort_t*)alloc((size_t)ROWS*PM*512*2);   // 64 MB
  ushort_t* f3      = (ushort_t*)alloc((size_t)ROWS*PM*512*2);   // 64 MB
  float*    hbuf    = (float*)   alloc((size_t)ROWS*PDM*4);
  float*    resid   = (float*)   alloc((size_t)ROWS*PDM*4);
  ushort_t* xlnb    = (ushort_t*)alloc((size_t)ROWS*PDM*2);
  float*    xz      = (float*)   alloc((size_t)ROWS*1536*4);
  float*    xin     = (float*)   alloc((size_t)ROWS*PDI*4);
  float*    dbl     = (float*)   alloc((size_t)ROWS*56*4);
  float*    dtg     = (float*)   alloc((size_t)ROWS*PDI*4);
  ushort_t* ybufb   = (ushort_t*)alloc((size_t)ROWS*PDI*2);
  ushort_t* wb      = (ushort_t*)alloc((size_t)CV_TOT*2);
  float*    dtwT    = (float*)   alloc((size_t)DTWT_TOT*4);
  float*    xpwT    = (float*)   alloc((size_t)XPWT_TOT*4);

  ushort_t* e1w2b  = wb;
  ushort_t* e2w1b  = wb + CV_O1;
  ushort_t* e2w2b  = wb + CV_O2;
  ushort_t* in_wb  = wb + CV_O3;
  ushort_t* out_wb = wb + CV_O4;

  prep_kernel<<<(PREP_TOT+255)/256, 256, 0, stream>>>(
      e1w2, e2w1, e2w2, in_w, out_w, dt_w, xp_w, wb, dtwT, xpwT);

  fps_kernel<<<PB, 256, 0, stream>>>(xyz, cidx);
  knn_kernel<<<ROWS, 64, 0, stream>>>(xyz, cidx, nbx, centerb);
  embed1_kernel<<<ROWS, 256, 0, stream>>>(nbx, e1w1, e1b1, bn1g, bn1b, e1w2b, e1b2, concat);

  mfma_gemm<4,4,1><<<dim3(4, 512), 256, 0, stream>>>(
      concat, 512, e2w1b, 512, nullptr, f3, 512, 512, e2b1, bn2g, bn2b);
  mfma_gemm<4,4,2><<<dim3(3, 512), 256, 0, stream>>>(
      f3, 512, e2w2b, 512, hbuf, nullptr, PDM, 512, e2b2, nullptr, nullptr);

  pos_kernel<<<ROWS, 128, 0, stream>>>(centerb, pw1, pb1, pw2, pb2, hbuf);

  for (int i = 0; i < 12; ++i) {
    prenorm_kernel<<<ROWS, 128, 0, stream>>>(hbuf, resid, lnw + i*384, lnb + i*384, xlnb, (i == 0) ? 1 : 0);
    mfma_gemm<4,4,0><<<dim3(12, 16), 256, 0, stream>>>(
        xlnb, PDM, in_wb + (size_t)i*1536*384, PDM, xz, nullptr, 1536, PDM,
        nullptr, nullptr, nullptr);
    cxd_kernel<<<ROWS, 256, 0, stream>>>(
        xz, conv_w + (size_t)i*768*4, conv_b + (size_t)i*768,
        xpwT + (size_t)i*49152, dtwT + (size_t)i*24*768, dt_b + (size_t)i*768,
        xin, dbl, dtg);
    scan_kernel<<<dim3(48, PB), 256, 0, stream>>>(
        dtg, xin, dbl, A_log + (size_t)i*768*16, Dp + (size_t)i*768, xz, ybufb);
    mfma_gemm<2,2,0><<<dim3(6, 32), 256, 0, stream>>>(
        ybufb, PDI, out_wb + (size_t)i*384*768, PDI, hbuf, nullptr, PDM, PDI,
        nullptr, nullptr, nullptr);
  }

  final_kernel<<<ROWS, 128, 0, stream>>>(hbuf, resid, fnw, fnb, (float*)d_out);
}